// Round 2
// baseline (258.718 us; speedup 1.0000x reference)
//
#include <hip/hip_runtime.h>
#include <stdint.h>

// BitDense: out_bit[u] = (32768 - 2*popcount(inputs ^ w[u]) + b[u]) < 0
// packed MSB-first per byte (numpy packbits), 4 bytes little-endian per uint32.
//
// ROUND 2 = MEASUREMENT PROBE: launch the identical idempotent kernel 4x.
// dur_us delta vs round 1 (194.5) = 3 * T_kernel. This disambiguates
// "kernel ~20us + ~175us harness overhead" from "kernel ~70us".

#define N_UNITS 32768
#define N_WORDS 1024 // uint32 words per unit row

__global__ __launch_bounds__(256) void bitdense_kernel(
    const uint32_t* __restrict__ inp,
    const uint32_t* __restrict__ w,
    const int*      __restrict__ bias,
    uint32_t*       __restrict__ out)
{
    const int tid  = threadIdx.x;
    const int lane = tid & 63;
    const int wv   = tid >> 6;

    __shared__ uint32_t sbool[32];

    // Preload the input row fragment for this lane (reused for all 8 units).
    const uint4* inp4 = (const uint4*)inp;
    const uint4 i0 = inp4[lane];
    const uint4 i1 = inp4[lane + 64];
    const uint4 i2 = inp4[lane + 128];
    const uint4 i3 = inp4[lane + 192];

    const int unit_base = (blockIdx.x << 5) + (wv << 3);

    int ones[8];

#pragma unroll 2
    for (int j = 0; j < 8; ++j) {
        const uint4* row4 = (const uint4*)(w + (size_t)(unit_base + j) * N_WORDS);
        const uint4 a0 = row4[lane];
        const uint4 a1 = row4[lane + 64];
        const uint4 a2 = row4[lane + 128];
        const uint4 a3 = row4[lane + 192];
        int c = 0;
        c += __popc(a0.x ^ i0.x) + __popc(a0.y ^ i0.y) + __popc(a0.z ^ i0.z) + __popc(a0.w ^ i0.w);
        c += __popc(a1.x ^ i1.x) + __popc(a1.y ^ i1.y) + __popc(a1.z ^ i1.z) + __popc(a1.w ^ i1.w);
        c += __popc(a2.x ^ i2.x) + __popc(a2.y ^ i2.y) + __popc(a2.z ^ i2.z) + __popc(a2.w ^ i2.w);
        c += __popc(a3.x ^ i3.x) + __popc(a3.y ^ i3.y) + __popc(a3.z ^ i3.z) + __popc(a3.w ^ i3.w);
        ones[j] = c;
    }

    // Wave-wide sum (64 lanes) per unit, then sign bit -> LDS.
#pragma unroll
    for (int j = 0; j < 8; ++j) {
        int c = ones[j];
#pragma unroll
        for (int s = 32; s > 0; s >>= 1) c += __shfl_xor(c, s, 64);
        if (lane == 0) {
            const int total = 32768 - 2 * c + bias[unit_base + j];
            sbool[(wv << 3) + j] = (total < 0) ? 1u : 0u;
        }
    }

    __syncthreads();

    // Pack 32 unit sign bits into one uint32.
    // unit m -> bit 8*(m>>3) + (7 - (m&7))  (packbits MSB-first, LE bytes)
    if (tid == 0) {
        uint32_t bits = 0;
#pragma unroll
        for (int m = 0; m < 32; ++m) {
            const uint32_t pos = (uint32_t)((m & 24) + (7 - (m & 7)));
            bits |= sbool[m] << pos;
        }
        out[blockIdx.x] = bits;
    }
}

extern "C" void kernel_launch(void* const* d_in, const int* in_sizes, int n_in,
                              void* d_out, int out_size, void* d_ws, size_t ws_size,
                              hipStream_t stream) {
    const uint32_t* inp = (const uint32_t*)d_in[0];
    const uint32_t* w   = (const uint32_t*)d_in[1];
    const int*      b   = (const int*)d_in[2];
    uint32_t*       out = (uint32_t*)d_out;

    // 4 identical idempotent launches: dur_us - 194.5 = 3 * T_kernel.
    bitdense_kernel<<<N_UNITS / 32, 256, 0, stream>>>(inp, w, b, out);
    bitdense_kernel<<<N_UNITS / 32, 256, 0, stream>>>(inp, w, b, out);
    bitdense_kernel<<<N_UNITS / 32, 256, 0, stream>>>(inp, w, b, out);
    bitdense_kernel<<<N_UNITS / 32, 256, 0, stream>>>(inp, w, b, out);
}

// Round 3
// 192.710 us; speedup vs baseline: 1.3425x; 1.3425x over previous
//
#include <hip/hip_runtime.h>
#include <stdint.h>

// BitDense: out_bit[u] = (32768 - 2*popcount(inputs ^ w[u]) + b[u]) < 0
// packed MSB-first per byte (numpy packbits), 4 bytes little-endian per uint32.
//
// Layout: one wave (64 lanes) per unit row (1024 uint32 = 4 KiB, read as
// 4x uint4 per lane -> fully coalesced dwordx4). 8 units per wave,
// 4 waves (256 thr) per block -> 32 units = exactly one output word per block.
// Grid = 32768/32 = 1024 blocks -> 16 waves/CU on 256 CUs.
//
// MEASURED (round-2 4x-launch probe): T_kernel = 21.4 us = 6.27 TB/s on the
// 134.2 MB of w -> ~99% of the 6.3 TB/s achievable HBM read ceiling (m13).
// L3-resident w does NOT serve faster than HBM rate. This is the roofline.

#define N_UNITS 32768
#define N_WORDS 1024 // uint32 words per unit row

__global__ __launch_bounds__(256) void bitdense_kernel(
    const uint32_t* __restrict__ inp,
    const uint32_t* __restrict__ w,
    const int*      __restrict__ bias,
    uint32_t*       __restrict__ out)
{
    const int tid  = threadIdx.x;
    const int lane = tid & 63;
    const int wv   = tid >> 6;

    __shared__ uint32_t sbool[32];

    // Preload the input row fragment for this lane (reused for all 8 units).
    const uint4* inp4 = (const uint4*)inp;
    const uint4 i0 = inp4[lane];
    const uint4 i1 = inp4[lane + 64];
    const uint4 i2 = inp4[lane + 128];
    const uint4 i3 = inp4[lane + 192];

    const int unit_base = (blockIdx.x << 5) + (wv << 3);

    int ones[8];

#pragma unroll 2
    for (int j = 0; j < 8; ++j) {
        const uint4* row4 = (const uint4*)(w + (size_t)(unit_base + j) * N_WORDS);
        const uint4 a0 = row4[lane];
        const uint4 a1 = row4[lane + 64];
        const uint4 a2 = row4[lane + 128];
        const uint4 a3 = row4[lane + 192];
        int c = 0;
        c += __popc(a0.x ^ i0.x) + __popc(a0.y ^ i0.y) + __popc(a0.z ^ i0.z) + __popc(a0.w ^ i0.w);
        c += __popc(a1.x ^ i1.x) + __popc(a1.y ^ i1.y) + __popc(a1.z ^ i1.z) + __popc(a1.w ^ i1.w);
        c += __popc(a2.x ^ i2.x) + __popc(a2.y ^ i2.y) + __popc(a2.z ^ i2.z) + __popc(a2.w ^ i2.w);
        c += __popc(a3.x ^ i3.x) + __popc(a3.y ^ i3.y) + __popc(a3.z ^ i3.z) + __popc(a3.w ^ i3.w);
        ones[j] = c;
    }

    // Wave-wide sum (64 lanes) per unit, then sign bit -> LDS.
#pragma unroll
    for (int j = 0; j < 8; ++j) {
        int c = ones[j];
#pragma unroll
        for (int s = 32; s > 0; s >>= 1) c += __shfl_xor(c, s, 64);
        if (lane == 0) {
            const int total = 32768 - 2 * c + bias[unit_base + j];
            sbool[(wv << 3) + j] = (total < 0) ? 1u : 0u;
        }
    }

    __syncthreads();

    // Pack 32 unit sign bits into one uint32.
    // unit m -> bit 8*(m>>3) + (7 - (m&7))  (packbits MSB-first, LE bytes)
    if (tid == 0) {
        uint32_t bits = 0;
#pragma unroll
        for (int m = 0; m < 32; ++m) {
            const uint32_t pos = (uint32_t)((m & 24) + (7 - (m & 7)));
            bits |= sbool[m] << pos;
        }
        out[blockIdx.x] = bits;
    }
}

extern "C" void kernel_launch(void* const* d_in, const int* in_sizes, int n_in,
                              void* d_out, int out_size, void* d_ws, size_t ws_size,
                              hipStream_t stream) {
    const uint32_t* inp = (const uint32_t*)d_in[0];
    const uint32_t* w   = (const uint32_t*)d_in[1];
    const int*      b   = (const int*)d_in[2];
    uint32_t*       out = (uint32_t*)d_out;

    bitdense_kernel<<<N_UNITS / 32, 256, 0, stream>>>(inp, w, b, out);
}